// Round 1
// baseline (132.039 us; speedup 1.0000x reference)
//
#include <hip/hip_runtime.h>

#define DIMH 9
#define SRF 24000.0f

// Phase 1: per-(b,k) prefix sum of per-frame phase increments, in double.
// P[(b*9+k)*T + t] = sum_{s<=t} rad[b,s,k], where rad includes rand_ini at s=0.
__global__ void scan_kernel(const float* __restrict__ f0,
                            const float* __restrict__ rand_ini,
                            double* __restrict__ P, int T) {
    extern __shared__ float sf0[];
    int b = blockIdx.x;
    for (int i = threadIdx.x; i < T; i += blockDim.x)
        sf0[i] = f0[(size_t)b * T + i];
    __syncthreads();
    int k = threadIdx.x;
    if (k < DIMH) {
        double acc = 0.0;
        float hk = (float)(k + 1);
        double* Pr = P + ((size_t)b * DIMH + k) * T;
        for (int t = 0; t < T; ++t) {
            float x = sf0[t] * hk / SRF;       // matches f0*(k+1)/SR in f32
            float rad = x - truncf(x);          // == fmodf(x,1) for x>=0
            if (t == 0) rad += rand_ini[b * DIMH + k];
            acc += (double)rad;
            Pr[t] = acc;
        }
    }
}

// Phase 2: one block per (b, frame t); 256 threads cover upp*9 = 2304 elems.
__global__ __launch_bounds__(256) void sine_kernel(
    const float* __restrict__ f0, const float* __restrict__ rand_ini,
    const float* __restrict__ noise_z, const double* __restrict__ P,
    float* __restrict__ out, int B, int T, int upp)
{
    int gb = blockIdx.x;          // b*T + t
    int b = gb / T;
    int t = gb - b * T;
    int tid = threadIdx.x;

    __shared__ double sP[DIMH];   // upp * P[t-1]  (0 at t==0)
    __shared__ float  srad[DIMH]; // rad[t] per harmonic

    float f0v = f0[(size_t)b * T + t];
    if (tid < DIMH) {
        float x = f0v * (float)(tid + 1) / SRF;
        float rad = x - truncf(x);
        if (t == 0) rad += rand_ini[b * DIMH + tid];
        srad[tid] = rad;
        sP[tid] = (t > 0) ? P[((size_t)b * DIMH + tid) * T + (t - 1)] * (double)upp
                          : 0.0;
    }
    __syncthreads();

    float uv   = (f0v > 0.0f) ? 1.0f : 0.0f;
    float namp = uv * 0.003f + (1.0f - uv) * (0.1f / 3.0f);

    size_t L = (size_t)T * (size_t)upp;
    float* out_sine  = out;
    float* out_uv    = out + (size_t)B * L * DIMH;
    float* out_noise = out_uv + (size_t)B * L;

    // uv: upp samples for this frame
    for (int i = tid; i < upp; i += 256)
        out_uv[(size_t)b * L + (size_t)t * upp + i] = uv;

    size_t frame_base = ((size_t)b * L + (size_t)t * upp) * DIMH;
    int nelem = upp * DIMH;       // 2304
    for (int e = tid; e < nelem; e += 256) {
        int rr = e / DIMH;        // sample-in-frame (magic-mul div)
        int k  = e - rr * DIMH;   // harmonic
        double C  = sP[k] + (double)(rr + 1) * (double)srad[k];
        double fr = C - (double)(long long)C;   // frac, C >= 0
#if __has_builtin(__builtin_amdgcn_sinf)
        float s = __builtin_amdgcn_sinf((float)fr) * 0.1f;  // v_sin_f32: revolutions in
#else
        float s = sinf(6.283185307179586f * (float)fr) * 0.1f;
#endif
        float nz = noise_z[frame_base + e];
        float no = namp * nz;
        out_sine[frame_base + e]  = fmaf(s, uv, no);
        out_noise[frame_base + e] = no;
    }
}

extern "C" void kernel_launch(void* const* d_in, const int* in_sizes, int n_in,
                              void* d_out, int out_size, void* d_ws, size_t ws_size,
                              hipStream_t stream) {
    const float* f0       = (const float*)d_in[0];
    const float* rand_ini = (const float*)d_in[1];
    const float* noise_z  = (const float*)d_in[2];
    float* out = (float*)d_out;

    int B = in_sizes[1] / DIMH;                       // 16
    int T = in_sizes[0] / B;                          // 800
    long long L = (long long)(in_sizes[2] / DIMH) / B; // 204800
    int upp = (int)(L / T);                           // 256

    double* P = (double*)d_ws;                        // B*9*T doubles (~0.9 MB)

    scan_kernel<<<B, 256, T * (int)sizeof(float), stream>>>(f0, rand_ini, P, T);
    sine_kernel<<<B * T, 256, 0, stream>>>(f0, rand_ini, noise_z, P, out, B, T, upp);
}